// Round 5
// baseline (203.192 us; speedup 1.0000x reference)
//
#include <hip/hip_runtime.h>
#include <stdint.h>

#define C_DIM   256
#define L_ANCH  8
#define M_INST  64
#define NPIX    32768
#define TILE_P  16       // pixels per block for qproj/oproj
#define LDSTR   264      // LDS row stride (shorts)
#define WSTR    40       // prep W-tile row stride (shorts)

typedef __attribute__((ext_vector_type(8))) short  short8;   // 8 x bf16
typedef __attribute__((ext_vector_type(4))) float  float4v;  // MFMA C/D

__device__ __forceinline__ float bf2f(unsigned short b) {
    union { unsigned u; float f; } x; x.u = ((unsigned)b) << 16; return x.f;
}
__device__ __forceinline__ unsigned short f2bf(float f) {
    union { unsigned u; float f; } x; x.f = f;
    unsigned u = x.u;
    return (unsigned short)((u + 0x7FFFu + ((u >> 16) & 1u)) >> 16);  // RNE
}
__device__ __forceinline__ ushort4 f4bf(float4 f) {
    ushort4 v; v.x = f2bf(f.x); v.y = f2bf(f.y); v.z = f2bf(f.z); v.w = f2bf(f.w);
    return v;
}

// ---------------------------------------------------------------------------
// prep (unchanged): K/V projection + weight bf16 conversion
// ---------------------------------------------------------------------------
__global__ __launch_bounds__(256) void prep_kernel(
    const float* __restrict__ anchors, const float* __restrict__ in_proj_w,
    const float* __restrict__ in_proj_b, const float* __restrict__ out_w,
    unsigned short* __restrict__ Kb, unsigned short* __restrict__ Vb,
    unsigned short* __restrict__ Wqb, unsigned short* __restrict__ Owb)
{
    __shared__ unsigned short Abuf[32 * LDSTR];
    __shared__ unsigned short Wtile[4][64 * WSTR];
    const int b = blockIdx.x, t = threadIdx.x;

    if (b >= 32) {
        const int id = (b - 32) * 256 + t;
        if (id < 16384) {
            float4 f = *((const float4*)in_proj_w + id);
            *((ushort4*)Wqb + id) = f4bf(f);
        } else {
            float4 f = *((const float4*)out_w + (id - 16384));
            *((ushort4*)Owb + (id - 16384)) = f4bf(f);
        }
        return;
    }

    const int mat = b >> 4, tile = b & 15, m0 = tile * 32;
#pragma unroll
    for (int i = 0; i < 8; ++i) {
        int id = t + i * 256;
        int row = id >> 6, c4 = id & 63;
        float4 f = *((const float4*)(anchors + (size_t)(m0 + row) * C_DIM) + c4);
        *(ushort4*)&Abuf[row * LDSTR + c4 * 4] = f4bf(f);
    }
    __syncthreads();

    const int wave = t >> 6, lane = t & 63, r16 = lane & 15, quad = lane >> 4;
    const int wbase = C_DIM + mat * C_DIM + wave * 64;
    unsigned short* Wl = &Wtile[wave][0];

    float4v acc[2][4];
#pragma unroll
    for (int mt = 0; mt < 2; ++mt)
#pragma unroll
        for (int nt = 0; nt < 4; ++nt)
#pragma unroll
            for (int r = 0; r < 4; ++r) acc[mt][nt][r] = 0.f;

    for (int ks = 0; ks < 8; ++ks) {
        const int rr = lane >> 3, cc = lane & 7;
#pragma unroll
        for (int i = 0; i < 8; ++i) {
            int row = rr + i * 8;
            float4 f = *((const float4*)(in_proj_w + (size_t)(wbase + row) * C_DIM + ks * 32) + cc);
            *(ushort4*)&Wl[row * WSTR + cc * 4] = f4bf(f);
        }
        const int c0 = ks * 32 + quad * 8;
        short8 afr[2], bfr[4];
#pragma unroll
        for (int mt = 0; mt < 2; ++mt)
            afr[mt] = *(const short8*)&Abuf[(mt * 16 + r16) * LDSTR + c0];
#pragma unroll
        for (int nt = 0; nt < 4; ++nt)
            bfr[nt] = *(const short8*)&Wl[(nt * 16 + r16) * WSTR + quad * 8];
#pragma unroll
        for (int mt = 0; mt < 2; ++mt)
#pragma unroll
            for (int nt = 0; nt < 4; ++nt)
                acc[mt][nt] = __builtin_amdgcn_mfma_f32_16x16x32_bf16(
                    afr[mt], bfr[nt], acc[mt][nt], 0, 0, 0);
    }

    unsigned short* dst = mat ? Vb : Kb;
#pragma unroll
    for (int nt = 0; nt < 4; ++nt) {
        const int col = wave * 64 + nt * 16 + r16;
        const float bias = in_proj_b[C_DIM + mat * C_DIM + col];
#pragma unroll
        for (int mt = 0; mt < 2; ++mt)
#pragma unroll
            for (int r = 0; r < 4; ++r) {
                int row = m0 + mt * 16 + quad * 4 + r;
                dst[(size_t)row * C_DIM + col] = f2bf(acc[mt][nt][r] + bias);
            }
    }
}

// ---------------------------------------------------------------------------
// qproj: Q = F @ Wq^T + bq  (bf16 to ws). 16 pixels/block, 2048 blocks.
// ---------------------------------------------------------------------------
__global__ __launch_bounds__(256, 4) void qproj_kernel(
    const float* __restrict__ features, const float* __restrict__ in_proj_b,
    const unsigned short* __restrict__ Wqb, unsigned short* __restrict__ Qb)
{
    __shared__ unsigned short Fbuf[TILE_P * LDSTR];   // 8.4 KB; F then Q-stash
    const int t = threadIdx.x;
    const int n0 = blockIdx.x * TILE_P;

    // stage F (fp32 -> bf16), 4 float4 per thread
#pragma unroll
    for (int i = 0; i < 4; ++i) {
        int id = t + i * 256;              // 1024 chunks
        int row = id >> 6, c4 = id & 63;
        float4 f = *((const float4*)(features + (size_t)(n0 + row) * C_DIM) + c4);
        *(ushort4*)&Fbuf[row * LDSTR + c4 * 4] = f4bf(f);
    }
    __syncthreads();

    const int wave = t >> 6, lane = t & 63, r16 = lane & 15, quad = lane >> 4;

    float4v acc[4];
#pragma unroll
    for (int nt = 0; nt < 4; ++nt)
#pragma unroll
        for (int r = 0; r < 4; ++r) acc[nt][r] = 0.f;

    for (int ks = 0; ks < 8; ++ks) {
        const int c0 = ks * 32 + quad * 8;
        short8 afr = *(const short8*)&Fbuf[r16 * LDSTR + c0];
#pragma unroll
        for (int nt = 0; nt < 4; ++nt) {
            int drow = wave * 64 + nt * 16 + r16;
            short8 bfr = *(const short8*)&Wqb[(size_t)drow * C_DIM + c0];
            acc[nt] = __builtin_amdgcn_mfma_f32_16x16x32_bf16(afr, bfr, acc[nt], 0, 0, 0);
        }
    }
    __syncthreads();   // F reads done, reuse Fbuf as Q stash

#pragma unroll
    for (int nt = 0; nt < 4; ++nt) {
        const int col = wave * 64 + nt * 16 + r16;
        const float bq = in_proj_b[col];
#pragma unroll
        for (int r = 0; r < 4; ++r)
            Fbuf[(quad * 4 + r) * LDSTR + col] = f2bf(acc[nt][r] + bq);
    }
    __syncthreads();

    // vectorized Q store: 16 rows x 32 ushort8 chunks = 512, 2 per thread
#pragma unroll
    for (int i = 0; i < 2; ++i) {
        int id = t + i * 256;
        int row = id >> 5, c8 = id & 31;
        *(short8*)&Qb[(size_t)(n0 + row) * C_DIM + c8 * 8] =
            *(const short8*)&Fbuf[row * LDSTR + c8 * 8];
    }
}

// ---------------------------------------------------------------------------
// attn: O = softmax(Q K^T / 16) V  (bf16 ws -> bf16 ws). No LDS, no barriers.
//   128 thr/block, 8 lanes/pixel -> 16 pixels/block, 2048 blocks.
// ---------------------------------------------------------------------------
__global__ __launch_bounds__(128) void attn_kernel(
    const int* __restrict__ inst,
    const unsigned short* __restrict__ Qb, const unsigned short* __restrict__ Kb,
    const unsigned short* __restrict__ Vb, unsigned short* __restrict__ Ob)
{
    const int t = threadIdx.x;
    const int p = t >> 3, s = t & 7;
    const int n = blockIdx.x * TILE_P + p;
    const int aidx = max(inst[n] - 1, 0);
    const unsigned short* Kp = Kb + (size_t)aidx * L_ANCH * C_DIM;
    const unsigned short* Vp = Vb + (size_t)aidx * L_ANCH * C_DIM;

    // hoist Q (reused for all 8 anchors)
    short8 qv[4];
#pragma unroll
    for (int ch = 0; ch < 4; ++ch)
        qv[ch] = *(const short8*)&Qb[(size_t)n * C_DIM + s * 32 + ch * 8];

    float sc[L_ANCH];
#pragma unroll
    for (int l = 0; l < L_ANCH; ++l) {
        float a0 = 0.f, a1 = 0.f, a2 = 0.f, a3 = 0.f;   // 4 indep chains
#pragma unroll
        for (int ch = 0; ch < 4; ++ch) {
            short8 kv = *(const short8*)&Kp[l * C_DIM + s * 32 + ch * 8];
            float pacc = 0.f;
#pragma unroll
            for (int j = 0; j < 8; ++j)
                pacc += bf2f(((const unsigned short*)&qv[ch])[j]) *
                        bf2f(((const unsigned short*)&kv)[j]);
            if (ch == 0) a0 = pacc; else if (ch == 1) a1 = pacc;
            else if (ch == 2) a2 = pacc; else a3 = pacc;
        }
        float partial = (a0 + a1) + (a2 + a3);
        partial += __shfl_down(partial, 1);
        partial += __shfl_down(partial, 2);
        partial += __shfl_down(partial, 4);
        sc[l] = partial;
    }

    float attn[L_ANCH];
    if (s == 0) {
        const float scale = 0.0625f;
        float mx = -1e30f;
#pragma unroll
        for (int l = 0; l < L_ANCH; ++l) { sc[l] *= scale; mx = fmaxf(mx, sc[l]); }
        float sum = 0.f;
#pragma unroll
        for (int l = 0; l < L_ANCH; ++l) { attn[l] = __expf(sc[l] - mx); sum += attn[l]; }
        float inv = 1.f / sum;
#pragma unroll
        for (int l = 0; l < L_ANCH; ++l) attn[l] *= inv;
    }
    const int base_lane = (t & 63) & ~7;
    float a_bc[L_ANCH];
#pragma unroll
    for (int l = 0; l < L_ANCH; ++l) a_bc[l] = __shfl(attn[l], base_lane);

    float o8[4][8];
#pragma unroll
    for (int ch = 0; ch < 4; ++ch)
#pragma unroll
        for (int j = 0; j < 8; ++j) o8[ch][j] = 0.f;
#pragma unroll
    for (int l = 0; l < L_ANCH; ++l) {
        float av = a_bc[l];
#pragma unroll
        for (int ch = 0; ch < 4; ++ch) {
            short8 vv = *(const short8*)&Vp[l * C_DIM + s * 32 + ch * 8];
#pragma unroll
            for (int j = 0; j < 8; ++j)
                o8[ch][j] += av * bf2f(((const unsigned short*)&vv)[j]);
        }
    }
#pragma unroll
    for (int ch = 0; ch < 4; ++ch) {
        unsigned short pk[8];
#pragma unroll
        for (int j = 0; j < 8; ++j) pk[j] = f2bf(o8[ch][j]);
        *(short8*)&Ob[(size_t)n * C_DIM + s * 32 + ch * 8] = *(const short8*)pk;
    }
}

// ---------------------------------------------------------------------------
// oproj: out = F + mask * (O @ out_w^T + out_b). 16 pixels/block, 2048 blocks.
// ---------------------------------------------------------------------------
__global__ __launch_bounds__(256, 4) void oproj_kernel(
    const float* __restrict__ features, const int* __restrict__ inst,
    const float* __restrict__ out_b, const unsigned short* __restrict__ Owb,
    const unsigned short* __restrict__ Ob, float* __restrict__ out)
{
    __shared__ unsigned short Obuf[TILE_P * LDSTR];   // O tile, then stash
    __shared__ int ilab[TILE_P];
    const int t = threadIdx.x;
    const int n0 = blockIdx.x * TILE_P;

    if (t < TILE_P) ilab[t] = inst[n0 + t];

    // stage O tile (bf16, straight copy): 512 ushort8 chunks, 2 per thread
#pragma unroll
    for (int i = 0; i < 2; ++i) {
        int id = t + i * 256;
        int row = id >> 5, c8 = id & 31;
        *(short8*)&Obuf[row * LDSTR + c8 * 8] =
            *(const short8*)&Ob[(size_t)(n0 + row) * C_DIM + c8 * 8];
    }
    __syncthreads();

    const int wave = t >> 6, lane = t & 63, r16 = lane & 15, quad = lane >> 4;

    float4v acc[4];
#pragma unroll
    for (int nt = 0; nt < 4; ++nt)
#pragma unroll
        for (int r = 0; r < 4; ++r) acc[nt][r] = 0.f;

    for (int ks = 0; ks < 8; ++ks) {
        const int c0 = ks * 32 + quad * 8;
        short8 afr = *(const short8*)&Obuf[r16 * LDSTR + c0];
#pragma unroll
        for (int nt = 0; nt < 4; ++nt) {
            int drow = wave * 64 + nt * 16 + r16;
            short8 bfr = *(const short8*)&Owb[(size_t)drow * C_DIM + c0];
            acc[nt] = __builtin_amdgcn_mfma_f32_16x16x32_bf16(afr, bfr, acc[nt], 0, 0, 0);
        }
    }
    __syncthreads();   // O reads done, reuse Obuf as stash

#pragma unroll
    for (int nt = 0; nt < 4; ++nt) {
        const int col = wave * 64 + nt * 16 + r16;
        const float bo = out_b[col];
#pragma unroll
        for (int r = 0; r < 4; ++r) {
            int row = quad * 4 + r;
            float val = (ilab[row] > 0) ? (acc[nt][r] + bo) : 0.f;
            Obuf[row * LDSTR + col] = f2bf(val);
        }
    }
    __syncthreads();

    // vectorized residual epilogue: 1024 float4 chunks, 4 per thread
#pragma unroll
    for (int i = 0; i < 4; ++i) {
        int id = t + i * 256;
        int row = id >> 6, c4 = id & 63;
        size_t gi = (size_t)(n0 + row) * C_DIM + c4 * 4;
        float4 f = *(const float4*)(features + gi);
        ushort4 v = *(const ushort4*)&Obuf[row * LDSTR + c4 * 4];
        float4 o;
        o.x = f.x + bf2f(v.x); o.y = f.y + bf2f(v.y);
        o.z = f.z + bf2f(v.z); o.w = f.w + bf2f(v.w);
        *(float4*)(out + gi) = o;
    }
}

// ---------------------------------------------------------------------------
extern "C" void kernel_launch(void* const* d_in, const int* in_sizes, int n_in,
                              void* d_out, int out_size, void* d_ws, size_t ws_size,
                              hipStream_t stream) {
    const float* anchors   = (const float*)d_in[0];
    const float* features  = (const float*)d_in[1];
    const int*   inst      = (const int*)d_in[2];
    const float* in_proj_w = (const float*)d_in[3];
    const float* in_proj_b = (const float*)d_in[4];
    const float* out_w     = (const float*)d_in[5];
    const float* out_b     = (const float*)d_in[6];
    float* out = (float*)d_out;

    unsigned short* Kb  = (unsigned short*)d_ws;              // 512*256
    unsigned short* Vb  = Kb  + M_INST * L_ANCH * C_DIM;      // 512*256
    unsigned short* Wqb = Vb  + M_INST * L_ANCH * C_DIM;      // 256*256
    unsigned short* Owb = Wqb + C_DIM * C_DIM;                // 256*256
    unsigned short* Qb  = Owb + C_DIM * C_DIM;                // 32768*256 bf16 (16.8 MB)
    unsigned short* Ob  = Qb  + (size_t)NPIX * C_DIM;         // 32768*256 bf16 (16.8 MB)

    prep_kernel<<<160, 256, 0, stream>>>(anchors, in_proj_w, in_proj_b, out_w,
                                         Kb, Vb, Wqb, Owb);
    qproj_kernel<<<NPIX / TILE_P, 256, 0, stream>>>(features, in_proj_b, Wqb, Qb);
    attn_kernel<<<NPIX / TILE_P, 128, 0, stream>>>(inst, Qb, Kb, Vb, Ob);
    oproj_kernel<<<NPIX / TILE_P, 256, 0, stream>>>(features, inst, out_b, Owb, Ob, out);
}

// Round 6
// 165.122 us; speedup vs baseline: 1.2306x; 1.2306x over previous
//
#include <hip/hip_runtime.h>
#include <stdint.h>

#define C_DIM   256
#define L_ANCH  8
#define M_INST  64
#define NPIX    32768
#define TILE_M  64       // pixels per fused block (1024 threads)
#define LDSTR   264      // Fbuf row stride (shorts): 528 B
#define SSTR    260      // stash row stride (shorts)
#define WSTR    40       // prep W-tile row stride (shorts)

typedef __attribute__((ext_vector_type(8))) short  short8;   // 8 x bf16
typedef __attribute__((ext_vector_type(4))) float  float4v;  // MFMA C/D

__device__ __forceinline__ float bf2f(unsigned short b) {
    union { unsigned u; float f; } x; x.u = ((unsigned)b) << 16; return x.f;
}
__device__ __forceinline__ unsigned short f2bf(float f) {
    union { unsigned u; float f; } x; x.f = f;
    unsigned u = x.u;
    return (unsigned short)((u + 0x7FFFu + ((u >> 16) & 1u)) >> 16);  // RNE
}
__device__ __forceinline__ ushort4 f4bf(float4 f) {
    ushort4 v; v.x = f2bf(f.x); v.y = f2bf(f.y); v.z = f2bf(f.z); v.w = f2bf(f.w);
    return v;
}

// ---------------------------------------------------------------------------
// prep (unchanged): K/V projection + weight bf16 conversion
// ---------------------------------------------------------------------------
__global__ __launch_bounds__(256) void prep_kernel(
    const float* __restrict__ anchors, const float* __restrict__ in_proj_w,
    const float* __restrict__ in_proj_b, const float* __restrict__ out_w,
    unsigned short* __restrict__ Kb, unsigned short* __restrict__ Vb,
    unsigned short* __restrict__ Wqb, unsigned short* __restrict__ Owb)
{
    __shared__ unsigned short Abuf[32 * LDSTR];
    __shared__ unsigned short Wtile[4][64 * WSTR];
    const int b = blockIdx.x, t = threadIdx.x;

    if (b >= 32) {
        const int id = (b - 32) * 256 + t;
        if (id < 16384) {
            float4 f = *((const float4*)in_proj_w + id);
            *((ushort4*)Wqb + id) = f4bf(f);
        } else {
            float4 f = *((const float4*)out_w + (id - 16384));
            *((ushort4*)Owb + (id - 16384)) = f4bf(f);
        }
        return;
    }

    const int mat = b >> 4, tile = b & 15, m0 = tile * 32;
#pragma unroll
    for (int i = 0; i < 8; ++i) {
        int id = t + i * 256;
        int row = id >> 6, c4 = id & 63;
        float4 f = *((const float4*)(anchors + (size_t)(m0 + row) * C_DIM) + c4);
        *(ushort4*)&Abuf[row * LDSTR + c4 * 4] = f4bf(f);
    }
    __syncthreads();

    const int wave = t >> 6, lane = t & 63, r16 = lane & 15, quad = lane >> 4;
    const int wbase = C_DIM + mat * C_DIM + wave * 64;
    unsigned short* Wl = &Wtile[wave][0];

    float4v acc[2][4];
#pragma unroll
    for (int mt = 0; mt < 2; ++mt)
#pragma unroll
        for (int nt = 0; nt < 4; ++nt)
#pragma unroll
            for (int r = 0; r < 4; ++r) acc[mt][nt][r] = 0.f;

    for (int ks = 0; ks < 8; ++ks) {
        const int rr = lane >> 3, cc = lane & 7;
#pragma unroll
        for (int i = 0; i < 8; ++i) {
            int row = rr + i * 8;
            float4 f = *((const float4*)(in_proj_w + (size_t)(wbase + row) * C_DIM + ks * 32) + cc);
            *(ushort4*)&Wl[row * WSTR + cc * 4] = f4bf(f);
        }
        const int c0 = ks * 32 + quad * 8;
        short8 afr[2], bfr[4];
#pragma unroll
        for (int mt = 0; mt < 2; ++mt)
            afr[mt] = *(const short8*)&Abuf[(mt * 16 + r16) * LDSTR + c0];
#pragma unroll
        for (int nt = 0; nt < 4; ++nt)
            bfr[nt] = *(const short8*)&Wl[(nt * 16 + r16) * WSTR + quad * 8];
#pragma unroll
        for (int mt = 0; mt < 2; ++mt)
#pragma unroll
            for (int nt = 0; nt < 4; ++nt)
                acc[mt][nt] = __builtin_amdgcn_mfma_f32_16x16x32_bf16(
                    afr[mt], bfr[nt], acc[mt][nt], 0, 0, 0);
    }

    unsigned short* dst = mat ? Vb : Kb;
#pragma unroll
    for (int nt = 0; nt < 4; ++nt) {
        const int col = wave * 64 + nt * 16 + r16;
        const float bias = in_proj_b[C_DIM + mat * C_DIM + col];
#pragma unroll
        for (int mt = 0; mt < 2; ++mt)
#pragma unroll
            for (int r = 0; r < 4; ++r) {
                int row = m0 + mt * 16 + quad * 4 + r;
                dst[(size_t)row * C_DIM + col] = f2bf(acc[mt][nt][r] + bias);
            }
    }
}

// ---------------------------------------------------------------------------
// fused: 1024 threads (16 waves), 64 pixels/block, grid 512 = 2 blocks/CU
//        -> 32 waves/CU. LDS 67.3 KB/block (2 blocks = 134.6 <= 160).
//   stage F -> GEMM1 (wave w: rows (w&1)*32.., cols (w>>1)*32..) -> Q over F
//   -> attn (16 lanes/pixel) -> O in-place -> GEMM2 -> masked stash ->
//   vectorized residual epilogue
// ---------------------------------------------------------------------------
__global__ __launch_bounds__(1024, 4) void fused_kernel(
    const float* __restrict__ features, const int* __restrict__ inst,
    const float* __restrict__ in_proj_b, const float* __restrict__ out_b,
    const unsigned short* __restrict__ Wqb, const unsigned short* __restrict__ Owb,
    const unsigned short* __restrict__ Kb, const unsigned short* __restrict__ Vb,
    float* __restrict__ out)
{
    __shared__ unsigned short Fbuf[TILE_M * LDSTR];   // F -> Q -> O (33.8 KB)
    __shared__ unsigned short Stash[TILE_M * SSTR];   // GEMM2 result (33.3 KB)
    __shared__ int ilab[TILE_M];

    const int t = threadIdx.x;
    const int n0 = blockIdx.x * TILE_M;

    if (t < TILE_M) ilab[t] = inst[n0 + t];

    // ---- stage F tile bf16: 4096 float4 chunks, 4 per thread ----
#pragma unroll
    for (int i = 0; i < 4; ++i) {
        int id = t + i * 1024;
        int row = id >> 6, c4 = id & 63;
        float4 f = *((const float4*)(features + (size_t)(n0 + row) * C_DIM) + c4);
        *(ushort4*)&Fbuf[row * LDSTR + c4 * 4] = f4bf(f);
    }
    __syncthreads();   // (1) F + ilab ready

    const int wave = t >> 6, lane = t & 63, r16 = lane & 15, quad = lane >> 4;
    const int m0w = (wave & 1) * 32;        // row-group
    const int c0w = (wave >> 1) * 32;       // col-group

    // ---- GEMM1: Q[m0w..+32][c0w..+32] = F @ Wq^T ----
    float4v acc[2][2];
#pragma unroll
    for (int mt = 0; mt < 2; ++mt)
#pragma unroll
        for (int nt = 0; nt < 2; ++nt)
#pragma unroll
            for (int r = 0; r < 4; ++r) acc[mt][nt][r] = 0.f;

    for (int ks = 0; ks < 8; ++ks) {
        const int c0 = ks * 32 + quad * 8;
        short8 afr[2], bfr[2];
#pragma unroll
        for (int mt = 0; mt < 2; ++mt)
            afr[mt] = *(const short8*)&Fbuf[(m0w + mt * 16 + r16) * LDSTR + c0];
#pragma unroll
        for (int nt = 0; nt < 2; ++nt)
            bfr[nt] = *(const short8*)&Wqb[(size_t)(c0w + nt * 16 + r16) * C_DIM + c0];
#pragma unroll
        for (int mt = 0; mt < 2; ++mt)
#pragma unroll
            for (int nt = 0; nt < 2; ++nt)
                acc[mt][nt] = __builtin_amdgcn_mfma_f32_16x16x32_bf16(
                    afr[mt], bfr[nt], acc[mt][nt], 0, 0, 0);
    }
    __syncthreads();   // (2) all F reads done

    // ---- Q (+bq) over Fbuf ----
#pragma unroll
    for (int nt = 0; nt < 2; ++nt) {
        const int col = c0w + nt * 16 + r16;
        const float bq = in_proj_b[col];
#pragma unroll
        for (int mt = 0; mt < 2; ++mt)
#pragma unroll
            for (int r = 0; r < 4; ++r) {
                int row = m0w + mt * 16 + quad * 4 + r;
                Fbuf[row * LDSTR + col] = f2bf(acc[mt][nt][r] + bq);
            }
    }
    __syncthreads();   // (3) Q ready

    // ---- attention: 16 lanes/pixel, lane s covers 16 channels ----
    const int p = t >> 4, s = t & 15;
    const int aidx = max(ilab[p] - 1, 0);
    const unsigned short* Kp = Kb + (size_t)aidx * L_ANCH * C_DIM;
    const unsigned short* Vp = Vb + (size_t)aidx * L_ANCH * C_DIM;

    float sc[L_ANCH];
#pragma unroll
    for (int l = 0; l < L_ANCH; ++l) {
        float a0 = 0.f, a1 = 0.f;
#pragma unroll
        for (int ch = 0; ch < 2; ++ch) {
            int cbase = s * 16 + ch * 8;
            short8 kv = *(const short8*)&Kp[l * C_DIM + cbase];
            short8 qv = *(const short8*)&Fbuf[p * LDSTR + cbase];
            float pacc = 0.f;
#pragma unroll
            for (int j = 0; j < 8; ++j)
                pacc += bf2f(((const unsigned short*)&qv)[j]) *
                        bf2f(((const unsigned short*)&kv)[j]);
            if (ch == 0) a0 = pacc; else a1 = pacc;
        }
        float partial = a0 + a1;
        partial += __shfl_down(partial, 1);
        partial += __shfl_down(partial, 2);
        partial += __shfl_down(partial, 4);
        partial += __shfl_down(partial, 8);
        sc[l] = partial;                 // valid on s==0
    }

    float attn[L_ANCH];
    if (s == 0) {
        const float scale = 0.0625f;     // 1/sqrt(256)
        float mx = -1e30f;
#pragma unroll
        for (int l = 0; l < L_ANCH; ++l) { sc[l] *= scale; mx = fmaxf(mx, sc[l]); }
        float sum = 0.f;
#pragma unroll
        for (int l = 0; l < L_ANCH; ++l) { attn[l] = __expf(sc[l] - mx); sum += attn[l]; }
        float inv = 1.f / sum;
#pragma unroll
        for (int l = 0; l < L_ANCH; ++l) attn[l] *= inv;
    }
    const int base_lane = lane & ~15;
    float a_bc[L_ANCH];
#pragma unroll
    for (int l = 0; l < L_ANCH; ++l) a_bc[l] = __shfl(attn[l], base_lane);

    // ---- O = attn @ V, in-place over the Q bytes this lane read ----
#pragma unroll
    for (int ch = 0; ch < 2; ++ch) {
        int cbase = s * 16 + ch * 8;
        float o8[8];
#pragma unroll
        for (int j = 0; j < 8; ++j) o8[j] = 0.f;
#pragma unroll
        for (int l = 0; l < L_ANCH; ++l) {
            short8 vv = *(const short8*)&Vp[l * C_DIM + cbase];
            float av = a_bc[l];
#pragma unroll
            for (int j = 0; j < 8; ++j)
                o8[j] += av * bf2f(((const unsigned short*)&vv)[j]);
        }
        unsigned short pk[8];
#pragma unroll
        for (int j = 0; j < 8; ++j) pk[j] = f2bf(o8[j]);
        *(short8*)&Fbuf[p * LDSTR + cbase] = *(const short8*)pk;
    }
    __syncthreads();   // (4) O ready

    // ---- GEMM2: O @ out_w^T ----
    float4v acc2[2][2];
#pragma unroll
    for (int mt = 0; mt < 2; ++mt)
#pragma unroll
        for (int nt = 0; nt < 2; ++nt)
#pragma unroll
            for (int r = 0; r < 4; ++r) acc2[mt][nt][r] = 0.f;

    for (int ks = 0; ks < 8; ++ks) {
        const int c0 = ks * 32 + quad * 8;
        short8 afr[2], bfr[2];
#pragma unroll
        for (int mt = 0; mt < 2; ++mt)
            afr[mt] = *(const short8*)&Fbuf[(m0w + mt * 16 + r16) * LDSTR + c0];
#pragma unroll
        for (int nt = 0; nt < 2; ++nt)
            bfr[nt] = *(const short8*)&Owb[(size_t)(c0w + nt * 16 + r16) * C_DIM + c0];
#pragma unroll
        for (int mt = 0; mt < 2; ++mt)
#pragma unroll
            for (int nt = 0; nt < 2; ++nt)
                acc2[mt][nt] = __builtin_amdgcn_mfma_f32_16x16x32_bf16(
                    afr[mt], bfr[nt], acc2[mt][nt], 0, 0, 0);
    }

    // ---- masked val+bias -> Stash (separate region, no barrier needed) ----
#pragma unroll
    for (int nt = 0; nt < 2; ++nt) {
        const int col = c0w + nt * 16 + r16;
        const float bo = out_b[col];
#pragma unroll
        for (int mt = 0; mt < 2; ++mt)
#pragma unroll
            for (int r = 0; r < 4; ++r) {
                int row = m0w + mt * 16 + quad * 4 + r;
                float val = (ilab[row] > 0) ? (acc2[mt][nt][r] + bo) : 0.f;
                Stash[row * SSTR + col] = f2bf(val);
            }
    }
    __syncthreads();   // (5) stash ready

    // ---- vectorized residual epilogue: 4096 float4 chunks, 4 per thread ----
#pragma unroll
    for (int i = 0; i < 4; ++i) {
        int id = t + i * 1024;
        int row = id >> 6, c4 = id & 63;
        size_t gi = (size_t)(n0 + row) * C_DIM + c4 * 4;
        float4 f = *(const float4*)(features + gi);
        ushort4 v = *(const ushort4*)&Stash[row * SSTR + c4 * 4];
        float4 o;
        o.x = f.x + bf2f(v.x); o.y = f.y + bf2f(v.y);
        o.z = f.z + bf2f(v.z); o.w = f.w + bf2f(v.w);
        *(float4*)(out + gi) = o;
    }
}

// ---------------------------------------------------------------------------
extern "C" void kernel_launch(void* const* d_in, const int* in_sizes, int n_in,
                              void* d_out, int out_size, void* d_ws, size_t ws_size,
                              hipStream_t stream) {
    const float* anchors   = (const float*)d_in[0];
    const float* features  = (const float*)d_in[1];
    const int*   inst      = (const int*)d_in[2];
    const float* in_proj_w = (const float*)d_in[3];
    const float* in_proj_b = (const float*)d_in[4];
    const float* out_w     = (const float*)d_in[5];
    const float* out_b     = (const float*)d_in[6];
    float* out = (float*)d_out;

    unsigned short* Kb  = (unsigned short*)d_ws;              // 512*256 bf16
    unsigned short* Vb  = Kb  + M_INST * L_ANCH * C_DIM;      // 512*256
    unsigned short* Wqb = Vb  + M_INST * L_ANCH * C_DIM;      // 256*256
    unsigned short* Owb = Wqb + C_DIM * C_DIM;                // 256*256

    prep_kernel<<<160, 256, 0, stream>>>(anchors, in_proj_w, in_proj_b, out_w,
                                         Kb, Vb, Wqb, Owb);
    fused_kernel<<<NPIX / TILE_M, 1024, 0, stream>>>(
        features, inst, in_proj_b, out_b, Wqb, Owb, Kb, Vb, out);
}